// Round 9
// baseline (248.353 us; speedup 1.0000x reference)
//
#include <hip/hip_runtime.h>
#include <math.h>

// DepthToVoxelConverter: B=32, (B,4,512,512) fp32 -> (B,4,64^3) fp32
// out ch0 = occupancy, ch1..3 = mean rgb per voxel.
//
// History:
//  R1: f32 atomics into d_out: scatter 430us (19.5G atomics/s; 32B-sector
//      dirty tracking established: WRITE 245MB = 8.4M x ~30B).
//  R2: packed 2x u64 atomics in ws: scatter 303us (14G/s).
//  R3: XCD-affinity swizzle: NEUTRAL -> atomics memory-side; op-rate wall.
//  R4: binning by (b,ix) + LDS accumulate: 301us.
//  R5: fixed-capacity buckets (CAP=30000), no count/scan: 287us.
//  R6: LDS-staged bucket-sorted flush + 4096 lighter blocks: 259us.
//  R7: append rgb register prefetch; reduce vectorized: 248us.
//  R8: reduce iy-quadrant split (8 blk/CU): 246us (NEUTRAL; redundant scans
//      cancel occupancy gain). Fixed harness tax ~140us; controllable
//      ~106us vs ~46us BW floor. append WRITE 40MB for 17MB payload (2.4x
//      partial-sector amplification) is the remaining counter-evidenced slack.
//  R9: pad per-(block,bin) segments to 4 entries (32B sector) with ~0ULL
//      sentinels -> sector-exclusive writes (amp -> 1.0x, no RFO partials);
//      bkt as uchar (same 7 blk/CU); 2-entry flush ILP; reduce skips
//      sentinels (1 cmp) and drops odd-tail (counts now multiple of 4).

constexpr int V = 64;
constexpr int V3 = V * V * V;           // 262144 = 2^18
constexpr int Wd = 512, Hd = 512;
constexpr int NPIX = Wd * Hd;           // 262144 = 2^18
constexpr int NBUCKET = 32 * 64;        // (b, ix) coarse buckets
constexpr unsigned CAP = 30000;         // entries per bucket (8B; %4==0)
constexpr float CQ = 32768.0f;          // color quant Q15
constexpr int PPB = 2048;               // pixels per append block
constexpr int CHUNKS = NPIX / PPB;      // 128 chunks per batch
constexpr int STAGE_MAX = PPB + 64 * 3; // worst-case padded total = 2240
constexpr unsigned long long SENTINEL = ~0ULL;  // unreachable: r16<=0x8000

__device__ __forceinline__ bool unproject(int w, int h, float d,
                                          int& ix, int& iy, int& iz) {
    // depth_valid = (d > 0) & (d < 10) & isfinite(d)
    if (!(d > 0.0f) || !(d < 10.0f) || !isfinite(d)) return false;
    const float fx = 256.0f, cx = 256.0f, cy = 256.0f;
    float x = (((float)w - cx) * d) / fx;
    float y = (((float)h - cy) * d) / fx;
    // np.round = RNE -> rintf; op order matches numpy rounding exactly.
    float tx = rintf(((x + 2.0f) * 0.25f) * 63.0f);
    float ty = rintf(((y + 2.0f) * 0.25f) * 63.0f);
    float tz = rintf(((d + 2.0f) * 0.25f) * 63.0f);
    ix = (int)tx; iy = (int)ty; iz = (int)tz;
    return !(ix < 0 || ix >= V || iy < 0 || iy >= V ||
             iz < 0 || iz >= V);
}

// ---- P0: cursor[kk] = kk*CAP (bump-allocator bases) ----
__global__ void dtv_cursor_init(unsigned* __restrict__ cursor) {
    int i = blockIdx.x * blockDim.x + threadIdx.x;   // 0..2047
    cursor[i] = (unsigned)i * CAP;
}

// ---- P1: append, LDS-staged + sector-aligned bucket-sorted flush ----
// 4096 blocks x 256 thr; block = (b, chunk of 2048 pixels).
// entry u64: [59:54]=iy [53:48]=iz [47:32]=r16 [31:16]=g16 [15:0]=b16
__global__ void __launch_bounds__(256)
dtv_append5(const float* __restrict__ rgbd,
            unsigned* __restrict__ cursor,
            unsigned long long* __restrict__ entries) {
    int blk = blockIdx.x;
    int b = blk >> 7, chunk = blk & (CHUNKS - 1), t = threadIdx.x;

    __shared__ unsigned lcnt[64];
    __shared__ unsigned lpre[64];    // padded exclusive prefix (stage slot base)
    __shared__ unsigned labs[64];    // global padded base per bin
    __shared__ unsigned totalPad;    // padded staged total
    __shared__ __align__(16) unsigned long long stage[STAGE_MAX];
    __shared__ unsigned char bkt[STAGE_MAX];

    if (t < 64) lcnt[t] = 0;
    __syncthreads();

    const float* bb = rgbd + (size_t)b * 4 * NPIX;
    const float4* r4 = (const float4*)(bb) + chunk * (PPB / 4);
    const float4* g4 = (const float4*)(bb + (size_t)NPIX) + chunk * (PPB / 4);
    const float4* b4 = (const float4*)(bb + (size_t)2 * NPIX) + chunk * (PPB / 4);
    const float4* d4 = (const float4*)(bb + (size_t)3 * NPIX) + chunk * (PPB / 4);
    int pbase = chunk * PPB;

    // Prefetch ALL planes into registers up front: loads in flight during
    // key computation, LDS atomics, barrier, and scan.
    float4 dv[2], rv[2], gv[2], bv[2];
#pragma unroll
    for (int i = 0; i < 2; ++i) dv[i] = d4[t + i * 256];
#pragma unroll
    for (int i = 0; i < 2; ++i) {
        rv[i] = r4[t + i * 256];
        gv[i] = g4[t + i * 256];
        bv[i] = b4[t + i * 256];
    }

    // Pass A: depth -> keys + block-local offsets.
    unsigned meta[8];   // (ix<<24)|(iy<<18)|(iz<<12)|off(12) ; ~0u invalid
#pragma unroll
    for (int i = 0; i < 2; ++i) {
        int p0 = pbase + 4 * (t + i * 256);
#pragma unroll
        for (int j = 0; j < 4; ++j) {
            float d = (j == 0) ? dv[i].x : (j == 1) ? dv[i].y
                    : (j == 2) ? dv[i].z : dv[i].w;
            int pix = p0 + j;
            int h = pix >> 9, w = pix & (Wd - 1);
            int ix, iy, iz;
            if (unproject(w, h, d, ix, iy, iz)) {
                unsigned off = atomicAdd(&lcnt[ix], 1u);
                meta[i * 4 + j] = ((unsigned)ix << 24) | ((unsigned)iy << 18) |
                                  ((unsigned)iz << 12) | off;
            } else {
                meta[i * 4 + j] = 0xFFFFFFFFu;
            }
        }
    }
    __syncthreads();

    // Wave 0: scan PADDED counts (4-entry / 32B sector granularity);
    // bump-alloc padded size; pre-fill this bin's pad slots with sentinels.
    if (t < 64) {
        unsigned c = lcnt[t];
        unsigned cp = (c + 3u) & ~3u;           // padded to 32B sector
        unsigned s = cp;
#pragma unroll
        for (int off = 1; off < 64; off <<= 1) {
            unsigned v = __shfl_up(s, off, 64);
            if (t >= off) s += v;
        }
        unsigned pre = s - cp;
        lpre[t] = pre;
        labs[t] = cp ? atomicAdd(&cursor[b * 64 + t], cp) : 0u;
        if (t == 63) totalPad = s;
        for (unsigned off = c; off < cp; ++off) {   // <=3 iterations
            stage[pre + off] = SENTINEL;
            bkt[pre + off] = (unsigned char)t;
        }
    }
    __syncthreads();

    // Pass B: pack from registers, write bucket-sorted into LDS staging.
#pragma unroll
    for (int i = 0; i < 2; ++i) {
#pragma unroll
        for (int j = 0; j < 4; ++j) {
            unsigned m = meta[i * 4 + j];
            if (m == 0xFFFFFFFFu) continue;
            unsigned ix = m >> 24, iy = (m >> 18) & 63u, iz = (m >> 12) & 63u;
            unsigned off = m & 0xFFFu;
            float r  = (j == 0) ? rv[i].x : (j == 1) ? rv[i].y
                     : (j == 2) ? rv[i].z : rv[i].w;
            float g  = (j == 0) ? gv[i].x : (j == 1) ? gv[i].y
                     : (j == 2) ? gv[i].z : gv[i].w;
            float bl = (j == 0) ? bv[i].x : (j == 1) ? bv[i].y
                     : (j == 2) ? bv[i].z : bv[i].w;
            unsigned long long r16 = (unsigned long long)(unsigned)rintf(r  * CQ);
            unsigned long long g16 = (unsigned long long)(unsigned)rintf(g  * CQ);
            unsigned long long b16 = (unsigned long long)(unsigned)rintf(bl * CQ);
            unsigned slot = lpre[ix] + off;
            stage[slot] = ((unsigned long long)iy << 54) |
                          ((unsigned long long)iz << 48) |
                          (r16 << 32) | (g16 << 16) | b16;
            bkt[slot] = (unsigned char)ix;
        }
    }
    __syncthreads();

    // Flush: sector-aligned segments; 2 entries/thread/iter for ILP.
    unsigned tp = totalPad;
    unsigned kb = (unsigned)(b * 64);
    for (unsigned e0 = t * 2; e0 < tp; e0 += 512) {
#pragma unroll
        for (int q = 0; q < 2; ++q) {
            unsigned e = e0 + q;
            if (e >= tp) break;
            unsigned ix = bkt[e];
            unsigned pos = labs[ix] + (e - lpre[ix]);
            if (pos < (kb + ix + 1) * CAP)        // capacity guard
                entries[(size_t)pos] = stage[e];
        }
    }
}

// ---- P2: 4 blocks per (b,ix) coarse bucket, each owns iy-quadrant ----
// 8192 blocks x 256 thr, 16KiB LDS -> 8 blocks/CU resident.
__global__ void __launch_bounds__(256)
dtv_reduce5(const ulonglong2* __restrict__ entries2,
            const unsigned* __restrict__ cursor,
            float* __restrict__ out) {
    int bq = blockIdx.x;               // 0..8191
    int kk = bq >> 2;                  // coarse bucket (b,ix)
    unsigned quad = (unsigned)(bq & 3);
    int b = kk >> 6, ix = kk & 63, t = threadIdx.x;

    __shared__ unsigned long long ldsA[1024];  // (count<<32)|rsum
    __shared__ unsigned long long ldsB[1024];  // (gsum <<32)|bsum

    unsigned basew = (unsigned)kk * CAP;            // u64 units
    unsigned cnt = cursor[kk] - basew;              // padded total (mult of 4)
    if (cnt > CAP) cnt = CAP;
    unsigned npair = cnt >> 1;
    size_t base2 = (size_t)kk * (CAP / 2);          // vec2 units

    // Prefetch first iteration's pair while zeroing LDS.
    ulonglong2 e2;
    if (t < (int)npair) e2 = entries2[base2 + t];

    ulonglong2* zA = (ulonglong2*)ldsA;             // 512 vec2
    ulonglong2* zB = (ulonglong2*)ldsB;
#pragma unroll
    for (int i = 0; i < 2; ++i) {
        zA[t + i * 256] = ulonglong2{0ULL, 0ULL};
        zB[t + i * 256] = ulonglong2{0ULL, 0ULL};
    }
    __syncthreads();

    auto accum = [&](unsigned long long p) {
        if (p == SENTINEL) return;                        // pad slot
        if (((unsigned)(p >> 58) & 3u) != quad) return;   // iy>>4 filter
        unsigned iy4 = (unsigned)(p >> 54) & 15u;         // iy & 15
        unsigned iz  = (unsigned)(p >> 48) & 63u;
        unsigned v = iy4 * 64u + iz;
        atomicAdd(&ldsA[v], (1ULL << 32) | ((p >> 32) & 0xFFFFULL));
        atomicAdd(&ldsB[v], (((p >> 16) & 0xFFFFULL) << 32) | (p & 0xFFFFULL));
    };

    for (unsigned j = t; j < npair; j += 256) {
        ulonglong2 cur = e2;
        unsigned jn = j + 256;
        if (jn < npair) e2 = entries2[base2 + jn];  // prefetch next
        accum(cur.x);
        accum(cur.y);
    }
    __syncthreads();

    float* p0 = out + (size_t)b * 4 * V3 + (size_t)ix * 4096 + quad * 1024;
    int v0 = t * 4;                                 // 4 consecutive voxels
    float4 o0, o1, o2, o3;
#pragma unroll
    for (int j = 0; j < 4; ++j) {
        unsigned long long A = ldsA[v0 + j], Bw = ldsB[v0 + j];
        unsigned c = (unsigned)(A >> 32);
        float occ = 0.0f, r = 0.0f, g = 0.0f, bl = 0.0f;
        if (c) {
            float inv = 1.0f / (CQ * (float)c);
            occ = 1.0f;
            r  = (float)(unsigned)(A  & 0xFFFFFFFFULL) * inv;
            g  = (float)(unsigned)(Bw >> 32)            * inv;
            bl = (float)(unsigned)(Bw & 0xFFFFFFFFULL)  * inv;
        }
        (&o0.x)[j] = occ; (&o1.x)[j] = r; (&o2.x)[j] = g; (&o3.x)[j] = bl;
    }
    ((float4*)(p0))[t]                  = o0;
    ((float4*)(p0 + (size_t)V3))[t]     = o1;
    ((float4*)(p0 + (size_t)2 * V3))[t] = o2;
    ((float4*)(p0 + (size_t)3 * V3))[t] = o3;
}

// ---------- fallback (generic B / tiny ws): proven R1 path ----------
__global__ void dtv_scatter_f32(const float* __restrict__ rgbd,
                                float* __restrict__ acc) {
    int idx = blockIdx.x * blockDim.x + threadIdx.x;
    int b   = idx >> 18;
    int pix = idx & (NPIX - 1);
    int h   = pix >> 9;
    int w   = pix & (Wd - 1);
    const float* base = rgbd + (size_t)b * 4 * NPIX;
    float d = base[(size_t)3 * NPIX + pix];
    int ix, iy, iz;
    if (!unproject(w, h, d, ix, iy, iz)) return;
    float r  = base[pix];
    float g  = base[(size_t)NPIX + pix];
    float bl = base[(size_t)2 * NPIX + pix];
    float* ob = acc + (size_t)b * 4 * V3;
    int vlin = (ix * V + iy) * V + iz;
    atomicAdd(ob + vlin, 1.0f);
    atomicAdd(ob + (size_t)V3 + vlin, r);
    atomicAdd(ob + (size_t)2 * V3 + vlin, g);
    atomicAdd(ob + (size_t)3 * V3 + vlin, bl);
}

__global__ void dtv_finalize_f32(float* __restrict__ out) {
    int idx = blockIdx.x * blockDim.x + threadIdx.x;
    int b    = idx >> 18;
    int vlin = idx & (V3 - 1);
    float* p = out + (size_t)b * 4 * V3;
    float c  = p[vlin];
    float r  = p[(size_t)V3 + vlin];
    float g  = p[(size_t)2 * V3 + vlin];
    float bl = p[(size_t)3 * V3 + vlin];
    bool occ = (c > 0.0f);
    p[vlin]                  = occ ? 1.0f : 0.0f;
    p[(size_t)V3 + vlin]     = occ ? (r / c)  : 0.0f;
    p[(size_t)2 * V3 + vlin] = occ ? (g / c)  : 0.0f;
    p[(size_t)3 * V3 + vlin] = occ ? (bl / c) : 0.0f;
}

extern "C" void kernel_launch(void* const* d_in, const int* in_sizes, int n_in,
                              void* d_out, int out_size, void* d_ws, size_t ws_size,
                              hipStream_t stream) {
    const float* rgbd = (const float*)d_in[0];
    float* out = (float*)d_out;
    const int B = in_sizes[0] / (4 * NPIX);   // 32

    // ws layout: [0, 8K) cursor | [8K, 8K + NBUCKET*CAP*8) entries (~491.5MB)
    size_t need = 8192 + (size_t)NBUCKET * CAP * sizeof(unsigned long long);

    if (B == 32 && ws_size >= need) {
        unsigned* cursor = (unsigned*)d_ws;
        unsigned long long* entries =
            (unsigned long long*)((char*)d_ws + 8192);
        dtv_cursor_init<<<NBUCKET / 256, 256, 0, stream>>>(cursor);
        dtv_append5    <<<B * CHUNKS, 256, 0, stream>>>(rgbd, cursor, entries);
        dtv_reduce5    <<<NBUCKET * 4, 256, 0, stream>>>((const ulonglong2*)entries,
                                                         cursor, out);
    } else {
        hipMemsetAsync(d_out, 0, (size_t)out_size * sizeof(float), stream);
        int total_pix = B * NPIX;
        int total_vox = B * V3;
        dtv_scatter_f32 <<<(total_pix + 255) / 256, 256, 0, stream>>>(rgbd, out);
        dtv_finalize_f32<<<(total_vox + 255) / 256, 256, 0, stream>>>(out);
    }
}